// Round 1
// baseline (1099.986 us; speedup 1.0000x reference)
//
#include <hip/hip_runtime.h>
#include <math.h>

#define N_NODES 50000
#define N_EDGES 800000
#define IN_F 256
#define OUT_F 64
#define N_HEADS 8
#define SLOPE 0.2f

#define TN 64   // node tile for GEMM
#define KC 32   // k chunk

// h[n][head][f] = sum_k x[n][k] * W[head][k][f]
__global__ __launch_bounds__(256) void gemm_kernel(const float* __restrict__ x,
                                                   const float* __restrict__ W,
                                                   float* __restrict__ h_ws) {
    __shared__ float xs[TN][KC + 1];      // +1 pad: conflict-free scalar reads
    __shared__ float ws[KC][OUT_F];       // float4 reads, 16B aligned
    const int head = blockIdx.y;
    const int nb = blockIdx.x * TN;
    const int t = threadIdx.x;
    const int tf = t & 15;   // feature group (4 f each)
    const int tn = t >> 4;   // node group (4 n each)

    float acc[4][4];
#pragma unroll
    for (int i = 0; i < 4; i++)
#pragma unroll
        for (int j = 0; j < 4; j++) acc[i][j] = 0.f;

    const float* Wh = W + (size_t)head * IN_F * OUT_F;

    for (int k0 = 0; k0 < IN_F; k0 += KC) {
        // stage x tile: 64 nodes x 32 k (coalesced along k)
#pragma unroll
        for (int i = 0; i < (TN * KC) / 256; i++) {
            int idx = i * 256 + t;
            int n = idx >> 5, k = idx & 31;
            int node = nb + n;
            xs[n][k] = (node < N_NODES) ? x[(size_t)node * IN_F + k0 + k] : 0.f;
        }
        // stage W chunk: 32 k x 64 f (coalesced along f)
#pragma unroll
        for (int i = 0; i < (KC * OUT_F) / 256; i++) {
            int idx = i * 256 + t;
            int k = idx >> 6, f = idx & 63;
            ws[k][f] = Wh[(size_t)(k0 + k) * OUT_F + f];
        }
        __syncthreads();
#pragma unroll
        for (int k = 0; k < KC; k++) {
            const float4 wq = *(const float4*)(&ws[k][tf * 4]);
#pragma unroll
            for (int i = 0; i < 4; i++) {
                float xv = xs[tn * 4 + i][k];
                acc[i][0] = fmaf(xv, wq.x, acc[i][0]);
                acc[i][1] = fmaf(xv, wq.y, acc[i][1]);
                acc[i][2] = fmaf(xv, wq.z, acc[i][2]);
                acc[i][3] = fmaf(xv, wq.w, acc[i][3]);
            }
        }
        __syncthreads();
    }
#pragma unroll
    for (int i = 0; i < 4; i++) {
        int node = nb + tn * 4 + i;
        if (node < N_NODES) {
            float4 v = make_float4(acc[i][0], acc[i][1], acc[i][2], acc[i][3]);
            *(float4*)&h_ws[((size_t)node * N_HEADS + head) * OUT_F + tf * 4] = v;
        }
    }
}

// a_self[n,h] = h[n,h,:] . a[h,0,:] ; a_neigh likewise with a[h,1,:]
__global__ __launch_bounds__(256) void adot_kernel(const float* __restrict__ h_ws,
                                                   const float* __restrict__ a,
                                                   float* __restrict__ a_self,
                                                   float* __restrict__ a_neigh) {
    int wid = blockIdx.x * 4 + (threadIdx.x >> 6);   // wid = n*H + head
    if (wid >= N_NODES * N_HEADS) return;
    int lane = threadIdx.x & 63;
    int head = wid & (N_HEADS - 1);
    float v = h_ws[(size_t)wid * OUT_F + lane];
    float s0 = v * a[(head * 2 + 0) * OUT_F + lane];
    float s1 = v * a[(head * 2 + 1) * OUT_F + lane];
#pragma unroll
    for (int off = 32; off; off >>= 1) {
        s0 += __shfl_down(s0, off, 64);
        s1 += __shfl_down(s1, off, 64);
    }
    if (lane == 0) { a_self[wid] = s0; a_neigh[wid] = s1; }
}

__global__ void hist_kernel(const int* __restrict__ dst, int* __restrict__ deg) {
    int e = blockIdx.x * 256 + threadIdx.x;
    if (e < N_EDGES) atomicAdd(&deg[dst[e]], 1);
}

#define SB 512
__global__ void scanA(const int* __restrict__ deg, int* __restrict__ start,
                      int* __restrict__ bsum) {
    __shared__ int tmp[SB];
    int t = threadIdx.x, i = blockIdx.x * SB + t;
    int v = (i < N_NODES) ? deg[i] : 0;
    tmp[t] = v;
    for (int off = 1; off < SB; off <<= 1) {
        __syncthreads();
        int add = (t >= off) ? tmp[t - off] : 0;
        __syncthreads();
        tmp[t] += add;
    }
    if (i < N_NODES) start[i] = tmp[t] - v;          // exclusive within block
    if (t == SB - 1) bsum[blockIdx.x] = tmp[SB - 1]; // block total
}

__global__ void scanB(int* __restrict__ bsum, int nb) {
    if (threadIdx.x == 0 && blockIdx.x == 0) {
        int run = 0;
        for (int b = 0; b < nb; b++) { int v = bsum[b]; bsum[b] = run; run += v; }
    }
}

__global__ void scanC(int* __restrict__ start, const int* __restrict__ bsum,
                      int* __restrict__ cursor) {
    int i = blockIdx.x * SB + threadIdx.x;
    if (i < N_NODES) {
        int s = start[i] + bsum[blockIdx.x];
        start[i] = s;
        cursor[i] = s;
    }
}

__global__ void fill_kernel(const int* __restrict__ src, const int* __restrict__ dst,
                            const float* __restrict__ M, int* __restrict__ cursor,
                            int* __restrict__ csr_src, float* __restrict__ csr_m) {
    int e = blockIdx.x * 256 + threadIdx.x;
    if (e < N_EDGES) {
        int d = dst[e];
        int pos = atomicAdd(&cursor[d], 1);
        csr_src[pos] = src[e];
        csr_m[pos] = M[e];
    }
}

// One wave per (node, head); lane = output feature. Fused softmax+aggregate:
// h_prime = (sum_e w_e * h[src_e]) / (sum_e w_e), w_e = exp(lrelu(as+an)*m)
__global__ __launch_bounds__(256) void agg_kernel(const float* __restrict__ h_ws,
                                                  const float* __restrict__ a_self,
                                                  const float* __restrict__ a_neigh,
                                                  const int* __restrict__ start,
                                                  const int* __restrict__ deg,
                                                  const int* __restrict__ csr_src,
                                                  const float* __restrict__ csr_m,
                                                  float* __restrict__ out) {
    int wid = blockIdx.x * 4 + (threadIdx.x >> 6);   // wid = n*H + head
    if (wid >= N_NODES * N_HEADS) return;
    int lane = threadIdx.x & 63;
    int n = wid >> 3;
    int head = wid & (N_HEADS - 1);

    int s0 = start[n];
    int d = deg[n];
    float an = a_neigh[(size_t)n * N_HEADS + head];

    float acc = 0.f, den = 0.f;
    for (int j = 0; j < d; j++) {
        int s = csr_src[s0 + j];
        float m = csr_m[s0 + j];
        float as = a_self[(size_t)s * N_HEADS + head];
        float e = as + an;
        e = (e > 0.f) ? e : SLOPE * e;
        float w = expf(e * m);
        den += w;
        acc = fmaf(w, h_ws[((size_t)s * N_HEADS + head) * OUT_F + lane], acc);
    }
    float r = acc / (den + 1e-16f);
    float o = (r > 0.f) ? r : expm1f(r);   // elu, alpha=1
    out[((size_t)n * N_HEADS + head) * OUT_F + lane] = o;
}

extern "C" void kernel_launch(void* const* d_in, const int* in_sizes, int n_in,
                              void* d_out, int out_size, void* d_ws, size_t ws_size,
                              hipStream_t stream) {
    const float* x   = (const float*)d_in[0];
    const int*   src = (const int*)d_in[1];
    const int*   dst = (const int*)d_in[2];
    const float* M   = (const float*)d_in[3];
    const float* W   = (const float*)d_in[4];
    const float* a   = (const float*)d_in[5];
    float* out = (float*)d_out;

    char* p = (char*)d_ws;
    auto alloc = [&](size_t bytes) {
        char* r = p;
        p += (bytes + 255) & ~(size_t)255;
        return r;
    };
    float* h_ws    = (float*)alloc(sizeof(float) * (size_t)N_NODES * N_HEADS * OUT_F);
    float* a_self  = (float*)alloc(sizeof(float) * N_NODES * N_HEADS);
    float* a_neigh = (float*)alloc(sizeof(float) * N_NODES * N_HEADS);
    int*   deg     = (int*)alloc(sizeof(int) * N_NODES);
    int*   start   = (int*)alloc(sizeof(int) * N_NODES);
    int*   cursor  = (int*)alloc(sizeof(int) * N_NODES);
    int*   bsum    = (int*)alloc(sizeof(int) * 256);
    int*   csr_src = (int*)alloc(sizeof(int) * N_EDGES);
    float* csr_m   = (float*)alloc(sizeof(float) * N_EDGES);

    // --- CSR build ---
    hipMemsetAsync(deg, 0, sizeof(int) * N_NODES, stream);
    hist_kernel<<<(N_EDGES + 255) / 256, 256, 0, stream>>>(dst, deg);
    const int nsb = (N_NODES + SB - 1) / SB;
    scanA<<<nsb, SB, 0, stream>>>(deg, start, bsum);
    scanB<<<1, 64, 0, stream>>>(bsum, nsb);
    scanC<<<nsb, SB, 0, stream>>>(start, bsum, cursor);
    fill_kernel<<<(N_EDGES + 255) / 256, 256, 0, stream>>>(src, dst, M, cursor, csr_src, csr_m);

    // --- feature transform ---
    gemm_kernel<<<dim3((N_NODES + TN - 1) / TN, N_HEADS), 256, 0, stream>>>(x, W, h_ws);
    adot_kernel<<<(N_NODES * N_HEADS) / 4, 256, 0, stream>>>(h_ws, a, a_self, a_neigh);

    // --- fused softmax + aggregation + elu ---
    agg_kernel<<<(N_NODES * N_HEADS) / 4, 256, 0, stream>>>(h_ws, a_self, a_neigh,
                                                            start, deg, csr_src, csr_m, out);
}

// Round 2
// 783.761 us; speedup vs baseline: 1.4035x; 1.4035x over previous
//
#include <hip/hip_runtime.h>
#include <math.h>

#define N_NODES 50000
#define N_EDGES 800000
#define IN_F 256
#define OUT_F 64
#define N_HEADS 8
#define SLOPE 0.2f

#define TN 64   // node tile for GEMM
#define KC 32   // k chunk

// h[n][head][f] = sum_k x[n][k] * W[head][k][f]
__global__ __launch_bounds__(256) void gemm_kernel(const float* __restrict__ x,
                                                   const float* __restrict__ W,
                                                   float* __restrict__ h_ws) {
    __shared__ float xs[TN][KC + 1];      // +1 pad: conflict-free scalar reads
    __shared__ float ws[KC][OUT_F];       // float4 reads, 16B aligned
    const int head = blockIdx.y;
    const int nb = blockIdx.x * TN;
    const int t = threadIdx.x;
    const int tf = t & 15;   // feature group (4 f each)
    const int tn = t >> 4;   // node group (4 n each)

    float acc[4][4];
#pragma unroll
    for (int i = 0; i < 4; i++)
#pragma unroll
        for (int j = 0; j < 4; j++) acc[i][j] = 0.f;

    const float* Wh = W + (size_t)head * IN_F * OUT_F;

    for (int k0 = 0; k0 < IN_F; k0 += KC) {
#pragma unroll
        for (int i = 0; i < (TN * KC) / 256; i++) {
            int idx = i * 256 + t;
            int n = idx >> 5, k = idx & 31;
            int node = nb + n;
            xs[n][k] = (node < N_NODES) ? x[(size_t)node * IN_F + k0 + k] : 0.f;
        }
#pragma unroll
        for (int i = 0; i < (KC * OUT_F) / 256; i++) {
            int idx = i * 256 + t;
            int k = idx >> 6, f = idx & 63;
            ws[k][f] = Wh[(size_t)(k0 + k) * OUT_F + f];
        }
        __syncthreads();
#pragma unroll
        for (int k = 0; k < KC; k++) {
            const float4 wq = *(const float4*)(&ws[k][tf * 4]);
#pragma unroll
            for (int i = 0; i < 4; i++) {
                float xv = xs[tn * 4 + i][k];
                acc[i][0] = fmaf(xv, wq.x, acc[i][0]);
                acc[i][1] = fmaf(xv, wq.y, acc[i][1]);
                acc[i][2] = fmaf(xv, wq.z, acc[i][2]);
                acc[i][3] = fmaf(xv, wq.w, acc[i][3]);
            }
        }
        __syncthreads();
    }
#pragma unroll
    for (int i = 0; i < 4; i++) {
        int node = nb + tn * 4 + i;
        if (node < N_NODES) {
            float4 v = make_float4(acc[i][0], acc[i][1], acc[i][2], acc[i][3]);
            *(float4*)&h_ws[((size_t)node * N_HEADS + head) * OUT_F + tf * 4] = v;
        }
    }
}

// a_self[n,h] = h[n,h,:] . a[h,0,:] ; a_neigh likewise with a[h,1,:]
__global__ __launch_bounds__(256) void adot_kernel(const float* __restrict__ h_ws,
                                                   const float* __restrict__ a,
                                                   float* __restrict__ a_self,
                                                   float* __restrict__ a_neigh) {
    int wid = blockIdx.x * 4 + (threadIdx.x >> 6);   // wid = n*H + head
    if (wid >= N_NODES * N_HEADS) return;
    int lane = threadIdx.x & 63;
    int head = wid & (N_HEADS - 1);
    float v = h_ws[(size_t)wid * OUT_F + lane];
    float s0 = v * a[(head * 2 + 0) * OUT_F + lane];
    float s1 = v * a[(head * 2 + 1) * OUT_F + lane];
#pragma unroll
    for (int off = 32; off; off >>= 1) {
        s0 += __shfl_down(s0, off, 64);
        s1 += __shfl_down(s1, off, 64);
    }
    if (lane == 0) { a_self[wid] = s0; a_neigh[wid] = s1; }
}

__global__ void hist_kernel(const int* __restrict__ dst, int* __restrict__ deg) {
    int e = blockIdx.x * 256 + threadIdx.x;
    if (e < N_EDGES) atomicAdd(&deg[dst[e]], 1);
}

#define SB 512
__global__ void scanA(const int* __restrict__ deg, int* __restrict__ start,
                      int* __restrict__ bsum) {
    __shared__ int tmp[SB];
    int t = threadIdx.x, i = blockIdx.x * SB + t;
    int v = (i < N_NODES) ? deg[i] : 0;
    tmp[t] = v;
    for (int off = 1; off < SB; off <<= 1) {
        __syncthreads();
        int add = (t >= off) ? tmp[t - off] : 0;
        __syncthreads();
        tmp[t] += add;
    }
    if (i < N_NODES) start[i] = tmp[t] - v;
    if (t == SB - 1) bsum[blockIdx.x] = tmp[SB - 1];
}

__global__ void scanB(int* __restrict__ bsum, int nb) {
    if (threadIdx.x == 0 && blockIdx.x == 0) {
        int run = 0;
        for (int b = 0; b < nb; b++) { int v = bsum[b]; bsum[b] = run; run += v; }
    }
}

__global__ void scanC(int* __restrict__ start, const int* __restrict__ bsum,
                      int* __restrict__ cursor) {
    int i = blockIdx.x * SB + threadIdx.x;
    if (i < N_NODES) {
        int s = start[i] + bsum[blockIdx.x];
        start[i] = s;
        cursor[i] = s;
    }
}

__global__ void fill_kernel(const int* __restrict__ src, const int* __restrict__ dst,
                            const float* __restrict__ M, int* __restrict__ cursor,
                            int* __restrict__ csr_src, int* __restrict__ csr_dst,
                            float* __restrict__ csr_m) {
    int e = blockIdx.x * 256 + threadIdx.x;
    if (e < N_EDGES) {
        int d = dst[e];
        int pos = atomicAdd(&cursor[d], 1);
        csr_src[pos] = src[e];
        csr_dst[pos] = d;
        csr_m[pos] = M[e];
    }
}

// Lane-parallel edge weights: w[pos,head] = exp(lrelu(a_self[s]+a_neigh[d]) * m)
// 64-wide exp evaluation instead of wave-redundant exp in the gather loop.
__global__ __launch_bounds__(256) void wcalc_kernel(const int* __restrict__ csr_src,
                                                    const int* __restrict__ csr_dst,
                                                    const float* __restrict__ csr_m,
                                                    const float* __restrict__ a_self,
                                                    const float* __restrict__ a_neigh,
                                                    float* __restrict__ csr_w) {
    int t = blockIdx.x * 256 + threadIdx.x;
    if (t >= N_EDGES * N_HEADS) return;
    int pos = t >> 3, head = t & 7;
    int s = csr_src[pos];
    int d = csr_dst[pos];
    float m = csr_m[pos];
    float as = a_self[s * N_HEADS + head];   // 8 consecutive lanes -> 32B segment
    float an = a_neigh[d * N_HEADS + head];
    float e = as + an;
    e = (e > 0.f) ? e : SLOPE * e;
    csr_w[t] = __expf(e * m);
}

// One wave per (node, head). Wave split into 4 quadrants of 16 lanes;
// each quadrant processes one edge per iteration, each lane gathers float4
// (16B) of h[src] -> 1KB per global_load_dwordx4. Epilogue: shfl_xor
// cross-quadrant reduction, softmax divide, elu, float4 store.
__global__ __launch_bounds__(256) void agg_kernel(const float* __restrict__ h_ws,
                                                  const int* __restrict__ start,
                                                  const int* __restrict__ deg,
                                                  const int* __restrict__ csr_src,
                                                  const float* __restrict__ csr_w,
                                                  float* __restrict__ out) {
    int wid = blockIdx.x * 4 + (threadIdx.x >> 6);   // wid = n*H + head
    if (wid >= N_NODES * N_HEADS) return;
    int lane = threadIdx.x & 63;
    int n = wid >> 3;
    int head = wid & (N_HEADS - 1);
    int q = lane >> 4;      // edge sub-slot within wave
    int fl = lane & 15;     // feature group (4 floats)

    int s0 = start[n];
    int d = deg[n];

    const float* hb = h_ws + (size_t)head * OUT_F + fl * 4;

    float4 acc = make_float4(0.f, 0.f, 0.f, 0.f);
    float den = 0.f;
    for (int j = 0; j < d; j += 4) {
        int jj = j + q;
        int idx = s0 + ((jj < d) ? jj : (d - 1));   // clamp: valid memory
        int s = csr_src[idx];
        float w = csr_w[idx * N_HEADS + head];
        if (jj >= d) w = 0.f;                        // mask tail
        const float4 hv = *(const float4*)(hb + (size_t)s * (N_HEADS * OUT_F));
        den += w;
        acc.x = fmaf(w, hv.x, acc.x);
        acc.y = fmaf(w, hv.y, acc.y);
        acc.z = fmaf(w, hv.z, acc.z);
        acc.w = fmaf(w, hv.w, acc.w);
    }
    // cross-quadrant reduction (lanes l, l+16, l+32, l+48)
    den   += __shfl_xor(den, 16, 64);
    den   += __shfl_xor(den, 32, 64);
    acc.x += __shfl_xor(acc.x, 16, 64);
    acc.x += __shfl_xor(acc.x, 32, 64);
    acc.y += __shfl_xor(acc.y, 16, 64);
    acc.y += __shfl_xor(acc.y, 32, 64);
    acc.z += __shfl_xor(acc.z, 16, 64);
    acc.z += __shfl_xor(acc.z, 32, 64);
    acc.w += __shfl_xor(acc.w, 16, 64);
    acc.w += __shfl_xor(acc.w, 32, 64);

    if (q == 0) {
        float inv = 1.f / (den + 1e-16f);
        float4 r;
        r.x = acc.x * inv; r.y = acc.y * inv; r.z = acc.z * inv; r.w = acc.w * inv;
        r.x = (r.x > 0.f) ? r.x : expm1f(r.x);
        r.y = (r.y > 0.f) ? r.y : expm1f(r.y);
        r.z = (r.z > 0.f) ? r.z : expm1f(r.z);
        r.w = (r.w > 0.f) ? r.w : expm1f(r.w);
        *(float4*)&out[((size_t)n * N_HEADS + head) * OUT_F + fl * 4] = r;
    }
}

extern "C" void kernel_launch(void* const* d_in, const int* in_sizes, int n_in,
                              void* d_out, int out_size, void* d_ws, size_t ws_size,
                              hipStream_t stream) {
    const float* x   = (const float*)d_in[0];
    const int*   src = (const int*)d_in[1];
    const int*   dst = (const int*)d_in[2];
    const float* M   = (const float*)d_in[3];
    const float* W   = (const float*)d_in[4];
    const float* a   = (const float*)d_in[5];
    float* out = (float*)d_out;

    char* p = (char*)d_ws;
    auto alloc = [&](size_t bytes) {
        char* r = p;
        p += (bytes + 255) & ~(size_t)255;
        return r;
    };
    float* h_ws    = (float*)alloc(sizeof(float) * (size_t)N_NODES * N_HEADS * OUT_F);
    float* a_self  = (float*)alloc(sizeof(float) * N_NODES * N_HEADS);
    float* a_neigh = (float*)alloc(sizeof(float) * N_NODES * N_HEADS);
    int*   deg     = (int*)alloc(sizeof(int) * N_NODES);
    int*   start   = (int*)alloc(sizeof(int) * N_NODES);
    int*   cursor  = (int*)alloc(sizeof(int) * N_NODES);
    int*   bsum    = (int*)alloc(sizeof(int) * 256);
    int*   csr_src = (int*)alloc(sizeof(int) * N_EDGES);
    int*   csr_dst = (int*)alloc(sizeof(int) * N_EDGES);
    float* csr_m   = (float*)alloc(sizeof(float) * N_EDGES);
    float* csr_w   = (float*)alloc(sizeof(float) * (size_t)N_EDGES * N_HEADS);

    // --- CSR build ---
    hipMemsetAsync(deg, 0, sizeof(int) * N_NODES, stream);
    hist_kernel<<<(N_EDGES + 255) / 256, 256, 0, stream>>>(dst, deg);
    const int nsb = (N_NODES + SB - 1) / SB;
    scanA<<<nsb, SB, 0, stream>>>(deg, start, bsum);
    scanB<<<1, 64, 0, stream>>>(bsum, nsb);
    scanC<<<nsb, SB, 0, stream>>>(start, bsum, cursor);
    fill_kernel<<<(N_EDGES + 255) / 256, 256, 0, stream>>>(src, dst, M, cursor,
                                                           csr_src, csr_dst, csr_m);

    // --- feature transform ---
    gemm_kernel<<<dim3((N_NODES + TN - 1) / TN, N_HEADS), 256, 0, stream>>>(x, W, h_ws);
    adot_kernel<<<(N_NODES * N_HEADS) / 4, 256, 0, stream>>>(h_ws, a, a_self, a_neigh);

    // --- edge weights (lane-parallel exp) ---
    wcalc_kernel<<<(N_EDGES * N_HEADS + 255) / 256, 256, 0, stream>>>(
        csr_src, csr_dst, csr_m, a_self, a_neigh, csr_w);

    // --- fused softmax + aggregation + elu ---
    agg_kernel<<<(N_NODES * N_HEADS) / 4, 256, 0, stream>>>(h_ws, start, deg,
                                                            csr_src, csr_w, out);
}

// Round 3
// 652.278 us; speedup vs baseline: 1.6864x; 1.2016x over previous
//
#include <hip/hip_runtime.h>
#include <math.h>

#define N_NODES 50000
#define N_EDGES 800000
#define IN_F 256
#define OUT_F 64
#define N_HEADS 8
#define SLOPE 0.2f

typedef __attribute__((ext_vector_type(8))) __bf16 bf16x8;
typedef __attribute__((ext_vector_type(4))) __bf16 bf16x4;
typedef __attribute__((ext_vector_type(4))) float floatx4;

// x fp32 -> bf16, 4 elems/thread
__global__ __launch_bounds__(256) void cast_x_kernel(const float* __restrict__ x,
                                                     __bf16* __restrict__ xb) {
    int i = blockIdx.x * 256 + threadIdx.x;   // over 12.8M/4
    float4 v = ((const float4*)x)[i];
    bf16x4 o;
    o[0] = (__bf16)v.x; o[1] = (__bf16)v.y; o[2] = (__bf16)v.z; o[3] = (__bf16)v.w;
    *(bf16x4*)(xb + (size_t)i * 4) = o;
}

// W[h][k][n] fp32 -> Wt[h][n][k] bf16 (transpose so B-frag loads are contiguous in k)
__global__ __launch_bounds__(256) void cast_w_kernel(const float* __restrict__ W,
                                                     __bf16* __restrict__ Wt) {
    int i = blockIdx.x * 256 + threadIdx.x;
    if (i >= N_HEADS * IN_F * OUT_F) return;
    int n = i & (OUT_F - 1);
    int k = (i >> 6) & (IN_F - 1);
    int h = i >> 14;
    Wt[((size_t)h * OUT_F + n) * IN_F + k] = (__bf16)W[i];
}

// h[n][head][f] via MFMA. One wave per (32-node tile, head).
// A[m=lane&15][k=quad*8+j]; B[k=quad*8+j][n=lane&15]; D[row=quad*4+reg][col=lane&15].
__global__ __launch_bounds__(256) void mfma_gemm_kernel(const __bf16* __restrict__ xb,
                                                        const __bf16* __restrict__ Wt,
                                                        float* __restrict__ h_ws) {
    const int wid = blockIdx.x * 4 + (threadIdx.x >> 6);
    const int head = wid & 7;           // 8 consecutive waves share the x tile
    const int tile = wid >> 3;          // 0..1562
    if (tile >= 1563) return;
    const int n0 = tile * 32;
    const int lane = threadIdx.x & 63;
    const int l15 = lane & 15;
    const int quad = lane >> 4;

    floatx4 acc[2][4];
#pragma unroll
    for (int i = 0; i < 2; i++)
#pragma unroll
        for (int c = 0; c < 4; c++) acc[i][c] = floatx4{0.f, 0.f, 0.f, 0.f};

    int r0 = n0 + l15;                       // always < 50000 (max 49999)
    int r1 = n0 + 16 + l15;
    r1 = (r1 < N_NODES) ? r1 : (N_NODES - 1); // clamp tail tile
    const __bf16* xrow0 = xb + (size_t)r0 * IN_F + quad * 8;
    const __bf16* xrow1 = xb + (size_t)r1 * IN_F + quad * 8;
    const __bf16* wbase = Wt + ((size_t)head * OUT_F + l15) * IN_F + quad * 8;

#pragma unroll
    for (int k0 = 0; k0 < IN_F; k0 += 32) {
        bf16x8 a0 = *(const bf16x8*)(xrow0 + k0);
        bf16x8 a1 = *(const bf16x8*)(xrow1 + k0);
#pragma unroll
        for (int c = 0; c < 4; c++) {
            bf16x8 b = *(const bf16x8*)(wbase + (size_t)c * 16 * IN_F + k0);
            acc[0][c] = __builtin_amdgcn_mfma_f32_16x16x32_bf16(a0, b, acc[0][c], 0, 0, 0);
            acc[1][c] = __builtin_amdgcn_mfma_f32_16x16x32_bf16(a1, b, acc[1][c], 0, 0, 0);
        }
    }

#pragma unroll
    for (int i = 0; i < 2; i++) {
#pragma unroll
        for (int reg = 0; reg < 4; reg++) {
            int node = n0 + i * 16 + quad * 4 + reg;
            if (node < N_NODES) {
                float* ob = &h_ws[((size_t)node * N_HEADS + head) * OUT_F + l15];
#pragma unroll
                for (int c = 0; c < 4; c++) ob[c * 16] = acc[i][c][reg];
            }
        }
    }
}

// a_self[n,h] = h[n,h,:] . a[h,0,:] ; a_neigh likewise with a[h,1,:]
__global__ __launch_bounds__(256) void adot_kernel(const float* __restrict__ h_ws,
                                                   const float* __restrict__ a,
                                                   float* __restrict__ a_self,
                                                   float* __restrict__ a_neigh) {
    int wid = blockIdx.x * 4 + (threadIdx.x >> 6);   // wid = n*H + head
    if (wid >= N_NODES * N_HEADS) return;
    int lane = threadIdx.x & 63;
    int head = wid & (N_HEADS - 1);
    float v = h_ws[(size_t)wid * OUT_F + lane];
    float s0 = v * a[(head * 2 + 0) * OUT_F + lane];
    float s1 = v * a[(head * 2 + 1) * OUT_F + lane];
#pragma unroll
    for (int off = 32; off; off >>= 1) {
        s0 += __shfl_down(s0, off, 64);
        s1 += __shfl_down(s1, off, 64);
    }
    if (lane == 0) { a_self[wid] = s0; a_neigh[wid] = s1; }
}

__global__ void hist_kernel(const int* __restrict__ dst, int* __restrict__ deg) {
    int e = blockIdx.x * 256 + threadIdx.x;
    if (e < N_EDGES) atomicAdd(&deg[dst[e]], 1);
}

#define SB 512
__global__ void scanA(const int* __restrict__ deg, int* __restrict__ start,
                      int* __restrict__ bsum) {
    __shared__ int tmp[SB];
    int t = threadIdx.x, i = blockIdx.x * SB + t;
    int v = (i < N_NODES) ? deg[i] : 0;
    tmp[t] = v;
    for (int off = 1; off < SB; off <<= 1) {
        __syncthreads();
        int add = (t >= off) ? tmp[t - off] : 0;
        __syncthreads();
        tmp[t] += add;
    }
    if (i < N_NODES) start[i] = tmp[t] - v;
    if (t == SB - 1) bsum[blockIdx.x] = tmp[SB - 1];
}

__global__ void scanB(int* __restrict__ bsum, int nb) {
    if (threadIdx.x == 0 && blockIdx.x == 0) {
        int run = 0;
        for (int b = 0; b < nb; b++) { int v = bsum[b]; bsum[b] = run; run += v; }
    }
}

__global__ void scanC(int* __restrict__ start, const int* __restrict__ bsum,
                      int* __restrict__ cursor) {
    int i = blockIdx.x * SB + threadIdx.x;
    if (i < N_NODES) {
        int s = start[i] + bsum[blockIdx.x];
        start[i] = s;
        cursor[i] = s;
    }
}

__global__ void fill_kernel(const int* __restrict__ src, const int* __restrict__ dst,
                            const float* __restrict__ M, int* __restrict__ cursor,
                            int* __restrict__ csr_src, int* __restrict__ csr_dst,
                            float* __restrict__ csr_m) {
    int e = blockIdx.x * 256 + threadIdx.x;
    if (e < N_EDGES) {
        int d = dst[e];
        int pos = atomicAdd(&cursor[d], 1);
        csr_src[pos] = src[e];
        csr_dst[pos] = d;
        csr_m[pos] = M[e];
    }
}

// Lane-parallel edge weights: w[pos,head] = exp(lrelu(a_self[s]+a_neigh[d]) * m)
__global__ __launch_bounds__(256) void wcalc_kernel(const int* __restrict__ csr_src,
                                                    const int* __restrict__ csr_dst,
                                                    const float* __restrict__ csr_m,
                                                    const float* __restrict__ a_self,
                                                    const float* __restrict__ a_neigh,
                                                    float* __restrict__ csr_w) {
    int t = blockIdx.x * 256 + threadIdx.x;
    if (t >= N_EDGES * N_HEADS) return;
    int pos = t >> 3, head = t & 7;
    int s = csr_src[pos];
    int d = csr_dst[pos];
    float m = csr_m[pos];
    float as = a_self[s * N_HEADS + head];
    float an = a_neigh[d * N_HEADS + head];
    float e = as + an;
    e = (e > 0.f) ? e : SLOPE * e;
    csr_w[t] = __expf(e * m);
}

// One wave per (node, head); 4 quadrants x 16 lanes; float4 gather of h[src].
__global__ __launch_bounds__(256) void agg_kernel(const float* __restrict__ h_ws,
                                                  const int* __restrict__ start,
                                                  const int* __restrict__ deg,
                                                  const int* __restrict__ csr_src,
                                                  const float* __restrict__ csr_w,
                                                  float* __restrict__ out) {
    int wid = blockIdx.x * 4 + (threadIdx.x >> 6);   // wid = n*H + head
    if (wid >= N_NODES * N_HEADS) return;
    int lane = threadIdx.x & 63;
    int n = wid >> 3;
    int head = wid & (N_HEADS - 1);
    int q = lane >> 4;
    int fl = lane & 15;

    int s0 = start[n];
    int d = deg[n];

    const float* hb = h_ws + (size_t)head * OUT_F + fl * 4;

    float4 acc = make_float4(0.f, 0.f, 0.f, 0.f);
    float den = 0.f;
    for (int j = 0; j < d; j += 4) {
        int jj = j + q;
        int idx = s0 + ((jj < d) ? jj : (d - 1));
        int s = csr_src[idx];
        float w = csr_w[idx * N_HEADS + head];
        if (jj >= d) w = 0.f;
        const float4 hv = *(const float4*)(hb + (size_t)s * (N_HEADS * OUT_F));
        den += w;
        acc.x = fmaf(w, hv.x, acc.x);
        acc.y = fmaf(w, hv.y, acc.y);
        acc.z = fmaf(w, hv.z, acc.z);
        acc.w = fmaf(w, hv.w, acc.w);
    }
    den   += __shfl_xor(den, 16, 64);
    den   += __shfl_xor(den, 32, 64);
    acc.x += __shfl_xor(acc.x, 16, 64);
    acc.x += __shfl_xor(acc.x, 32, 64);
    acc.y += __shfl_xor(acc.y, 16, 64);
    acc.y += __shfl_xor(acc.y, 32, 64);
    acc.z += __shfl_xor(acc.z, 16, 64);
    acc.z += __shfl_xor(acc.z, 32, 64);
    acc.w += __shfl_xor(acc.w, 16, 64);
    acc.w += __shfl_xor(acc.w, 32, 64);

    if (q == 0) {
        float inv = 1.f / (den + 1e-16f);
        float4 r;
        r.x = acc.x * inv; r.y = acc.y * inv; r.z = acc.z * inv; r.w = acc.w * inv;
        r.x = (r.x > 0.f) ? r.x : expm1f(r.x);
        r.y = (r.y > 0.f) ? r.y : expm1f(r.y);
        r.z = (r.z > 0.f) ? r.z : expm1f(r.z);
        r.w = (r.w > 0.f) ? r.w : expm1f(r.w);
        *(float4*)&out[((size_t)n * N_HEADS + head) * OUT_F + fl * 4] = r;
    }
}

extern "C" void kernel_launch(void* const* d_in, const int* in_sizes, int n_in,
                              void* d_out, int out_size, void* d_ws, size_t ws_size,
                              hipStream_t stream) {
    const float* x   = (const float*)d_in[0];
    const int*   src = (const int*)d_in[1];
    const int*   dst = (const int*)d_in[2];
    const float* M   = (const float*)d_in[3];
    const float* W   = (const float*)d_in[4];
    const float* a   = (const float*)d_in[5];
    float* out = (float*)d_out;

    char* p = (char*)d_ws;
    auto alloc = [&](size_t bytes) {
        char* r = p;
        p += (bytes + 255) & ~(size_t)255;
        return r;
    };
    float*  h_ws    = (float*)alloc(sizeof(float) * (size_t)N_NODES * N_HEADS * OUT_F);
    float*  a_self  = (float*)alloc(sizeof(float) * N_NODES * N_HEADS);
    float*  a_neigh = (float*)alloc(sizeof(float) * N_NODES * N_HEADS);
    int*    deg     = (int*)alloc(sizeof(int) * N_NODES);
    int*    start   = (int*)alloc(sizeof(int) * N_NODES);
    int*    cursor  = (int*)alloc(sizeof(int) * N_NODES);
    int*    bsum    = (int*)alloc(sizeof(int) * 256);
    int*    csr_src = (int*)alloc(sizeof(int) * N_EDGES);
    int*    csr_dst = (int*)alloc(sizeof(int) * N_EDGES);
    float*  csr_m   = (float*)alloc(sizeof(float) * N_EDGES);
    float*  csr_w   = (float*)alloc(sizeof(float) * (size_t)N_EDGES * N_HEADS);
    __bf16* xb      = (__bf16*)alloc(sizeof(__bf16) * (size_t)N_NODES * IN_F);
    __bf16* Wt      = (__bf16*)alloc(sizeof(__bf16) * N_HEADS * IN_F * OUT_F);

    // --- casts (independent of CSR) ---
    cast_x_kernel<<<(N_NODES * IN_F / 4 + 255) / 256, 256, 0, stream>>>(x, xb);
    cast_w_kernel<<<(N_HEADS * IN_F * OUT_F + 255) / 256, 256, 0, stream>>>(W, Wt);

    // --- CSR build ---
    hipMemsetAsync(deg, 0, sizeof(int) * N_NODES, stream);
    hist_kernel<<<(N_EDGES + 255) / 256, 256, 0, stream>>>(dst, deg);
    const int nsb = (N_NODES + SB - 1) / SB;
    scanA<<<nsb, SB, 0, stream>>>(deg, start, bsum);
    scanB<<<1, 64, 0, stream>>>(bsum, nsb);
    scanC<<<nsb, SB, 0, stream>>>(start, bsum, cursor);
    fill_kernel<<<(N_EDGES + 255) / 256, 256, 0, stream>>>(src, dst, M, cursor,
                                                           csr_src, csr_dst, csr_m);

    // --- feature transform (bf16 MFMA) ---
    mfma_gemm_kernel<<<(1563 * N_HEADS + 3) / 4, 256, 0, stream>>>(xb, Wt, h_ws);
    adot_kernel<<<(N_NODES * N_HEADS) / 4, 256, 0, stream>>>(h_ws, a, a_self, a_neigh);

    // --- edge weights (lane-parallel exp) ---
    wcalc_kernel<<<(N_EDGES * N_HEADS + 255) / 256, 256, 0, stream>>>(
        csr_src, csr_dst, csr_m, a_self, a_neigh, csr_w);

    // --- fused softmax + aggregation + elu ---
    agg_kernel<<<(N_NODES * N_HEADS) / 4, 256, 0, stream>>>(h_ws, start, deg,
                                                            csr_src, csr_w, out);
}

// Round 4
// 531.502 us; speedup vs baseline: 2.0696x; 1.2272x over previous
//
#include <hip/hip_runtime.h>
#include <math.h>

#define N_NODES 50000
#define N_EDGES 800000
#define IN_F 256
#define OUT_F 64
#define N_HEADS 8
#define SLOPE 0.2f

typedef __attribute__((ext_vector_type(8))) __bf16 bf16x8;
typedef __attribute__((ext_vector_type(4))) __bf16 bf16x4;
typedef __attribute__((ext_vector_type(4))) float floatx4;

// x fp32 -> bf16, 4 elems/thread (grid exact: 50000*256/4/256 = 12500)
__global__ __launch_bounds__(256) void cast_x_kernel(const float* __restrict__ x,
                                                     __bf16* __restrict__ xb) {
    int i = blockIdx.x * 256 + threadIdx.x;
    float4 v = ((const float4*)x)[i];
    bf16x4 o;
    o[0] = (__bf16)v.x; o[1] = (__bf16)v.y; o[2] = (__bf16)v.z; o[3] = (__bf16)v.w;
    *(bf16x4*)(xb + (size_t)i * 4) = o;
}

// h fp32 [n][head][f] -> bf16 same layout (grid exact: 50000*512/4/256 = 25000)
__global__ __launch_bounds__(256) void cast_h_kernel(const float* __restrict__ h_ws,
                                                     __bf16* __restrict__ hb) {
    int i = blockIdx.x * 256 + threadIdx.x;
    float4 v = ((const float4*)h_ws)[i];
    bf16x4 o;
    o[0] = (__bf16)v.x; o[1] = (__bf16)v.y; o[2] = (__bf16)v.z; o[3] = (__bf16)v.w;
    *(bf16x4*)(hb + (size_t)i * 4) = o;
}

// W[h][k][n] fp32 -> Wt[h][n][k] bf16
__global__ __launch_bounds__(256) void cast_w_kernel(const float* __restrict__ W,
                                                     __bf16* __restrict__ Wt) {
    int i = blockIdx.x * 256 + threadIdx.x;
    if (i >= N_HEADS * IN_F * OUT_F) return;
    int n = i & (OUT_F - 1);
    int k = (i >> 6) & (IN_F - 1);
    int h = i >> 14;
    Wt[((size_t)h * OUT_F + n) * IN_F + k] = (__bf16)W[i];
}

// h[n][head][f] via MFMA. One wave per (32-node tile, head).
__global__ __launch_bounds__(256) void mfma_gemm_kernel(const __bf16* __restrict__ xb,
                                                        const __bf16* __restrict__ Wt,
                                                        float* __restrict__ h_ws) {
    const int wid = blockIdx.x * 4 + (threadIdx.x >> 6);
    const int head = wid & 7;
    const int tile = wid >> 3;
    if (tile >= 1563) return;
    const int n0 = tile * 32;
    const int lane = threadIdx.x & 63;
    const int l15 = lane & 15;
    const int quad = lane >> 4;

    floatx4 acc[2][4];
#pragma unroll
    for (int i = 0; i < 2; i++)
#pragma unroll
        for (int c = 0; c < 4; c++) acc[i][c] = floatx4{0.f, 0.f, 0.f, 0.f};

    int r0 = n0 + l15;
    int r1 = n0 + 16 + l15;
    r1 = (r1 < N_NODES) ? r1 : (N_NODES - 1);
    const __bf16* xrow0 = xb + (size_t)r0 * IN_F + quad * 8;
    const __bf16* xrow1 = xb + (size_t)r1 * IN_F + quad * 8;
    const __bf16* wbase = Wt + ((size_t)head * OUT_F + l15) * IN_F + quad * 8;

#pragma unroll
    for (int k0 = 0; k0 < IN_F; k0 += 32) {
        bf16x8 a0 = *(const bf16x8*)(xrow0 + k0);
        bf16x8 a1 = *(const bf16x8*)(xrow1 + k0);
#pragma unroll
        for (int c = 0; c < 4; c++) {
            bf16x8 b = *(const bf16x8*)(wbase + (size_t)c * 16 * IN_F + k0);
            acc[0][c] = __builtin_amdgcn_mfma_f32_16x16x32_bf16(a0, b, acc[0][c], 0, 0, 0);
            acc[1][c] = __builtin_amdgcn_mfma_f32_16x16x32_bf16(a1, b, acc[1][c], 0, 0, 0);
        }
    }

#pragma unroll
    for (int i = 0; i < 2; i++) {
#pragma unroll
        for (int reg = 0; reg < 4; reg++) {
            int node = n0 + i * 16 + quad * 4 + reg;
            if (node < N_NODES) {
                float* ob = &h_ws[((size_t)node * N_HEADS + head) * OUT_F + l15];
#pragma unroll
                for (int c = 0; c < 4; c++) ob[c * 16] = acc[i][c][reg];
            }
        }
    }
}

// a_self[n,h] = h[n,h,:] . a[h,0,:] ; a_neigh likewise with a[h,1,:]
__global__ __launch_bounds__(256) void adot_kernel(const float* __restrict__ h_ws,
                                                   const float* __restrict__ a,
                                                   float* __restrict__ a_self,
                                                   float* __restrict__ a_neigh) {
    int wid = blockIdx.x * 4 + (threadIdx.x >> 6);   // wid = n*H + head
    if (wid >= N_NODES * N_HEADS) return;
    int lane = threadIdx.x & 63;
    int head = wid & (N_HEADS - 1);
    float v = h_ws[(size_t)wid * OUT_F + lane];
    float s0 = v * a[(head * 2 + 0) * OUT_F + lane];
    float s1 = v * a[(head * 2 + 1) * OUT_F + lane];
#pragma unroll
    for (int off = 32; off; off >>= 1) {
        s0 += __shfl_down(s0, off, 64);
        s1 += __shfl_down(s1, off, 64);
    }
    if (lane == 0) { a_self[wid] = s0; a_neigh[wid] = s1; }
}

__global__ void hist_kernel(const int* __restrict__ dst, int* __restrict__ deg) {
    int e = blockIdx.x * 256 + threadIdx.x;
    if (e < N_EDGES) atomicAdd(&deg[dst[e]], 1);
}

#define SB 512
__global__ void scanA(const int* __restrict__ deg, int* __restrict__ start,
                      int* __restrict__ bsum) {
    __shared__ int tmp[SB];
    int t = threadIdx.x, i = blockIdx.x * SB + t;
    int v = (i < N_NODES) ? deg[i] : 0;
    tmp[t] = v;
    for (int off = 1; off < SB; off <<= 1) {
        __syncthreads();
        int add = (t >= off) ? tmp[t - off] : 0;
        __syncthreads();
        tmp[t] += add;
    }
    if (i < N_NODES) start[i] = tmp[t] - v;
    if (t == SB - 1) bsum[blockIdx.x] = tmp[SB - 1];
}

__global__ void scanB(int* __restrict__ bsum, int nb) {
    if (threadIdx.x == 0 && blockIdx.x == 0) {
        int run = 0;
        for (int b = 0; b < nb; b++) { int v = bsum[b]; bsum[b] = run; run += v; }
    }
}

__global__ void scanC(int* __restrict__ start, const int* __restrict__ bsum,
                      int* __restrict__ cursor) {
    int i = blockIdx.x * SB + threadIdx.x;
    if (i < N_NODES) {
        int s = start[i] + bsum[blockIdx.x];
        start[i] = s;
        cursor[i] = s;
    }
}

// pack {src, m-bits} into one int2 so the agg loop does a single 8B index load
__global__ void fill_kernel(const int* __restrict__ src, const int* __restrict__ dst,
                            const float* __restrict__ M, int* __restrict__ cursor,
                            int2* __restrict__ csr_sm) {
    int e = blockIdx.x * 256 + threadIdx.x;
    if (e < N_EDGES) {
        int d = dst[e];
        int pos = atomicAdd(&cursor[d], 1);
        csr_sm[pos] = make_int2(src[e], __float_as_int(M[e]));
    }
}

// One wave per node, ALL 8 heads per iteration. Lane l: head = l>>3,
// features (l&7)*8..+8. Per edge: one int2 {src,m} (prefetched), one 32B-group
// a_self gather, one 1024B fully-coalesced bf16 h-row gather (16B/lane).
// Lane-private acc + per-head den (identical across the 8 lanes of a head) ->
// zero cross-lane reduction in the epilogue.
__global__ __launch_bounds__(256) void agg_kernel(const __bf16* __restrict__ hb,
                                                  const float* __restrict__ a_self,
                                                  const float* __restrict__ a_neigh,
                                                  const int* __restrict__ start,
                                                  const int* __restrict__ deg,
                                                  const int2* __restrict__ csr_sm,
                                                  float* __restrict__ out) {
    int n = blockIdx.x * 4 + (threadIdx.x >> 6);
    if (n >= N_NODES) return;
    const int lane = threadIdx.x & 63;
    const int head = lane >> 3;

    const int s0 = start[n];
    const int d = deg[n];
    const float an = a_neigh[n * N_HEADS + head];

    float facc[8];
#pragma unroll
    for (int k = 0; k < 8; k++) facc[k] = 0.f;
    float den = 0.f;

    int2 sm = (d > 0) ? csr_sm[s0] : make_int2(0, 0);
    for (int j = 0; j < d; j++) {
        const int s = sm.x;
        const float m = __int_as_float(sm.y);
        if (j + 1 < d) sm = csr_sm[s0 + j + 1];     // prefetch next index pair
        float e = a_self[s * N_HEADS + head] + an;
        e = (e > 0.f) ? e : SLOPE * e;
        const float w = __expf(e * m);
        const bf16x8 hv = *(const bf16x8*)(hb + (size_t)s * (N_HEADS * OUT_F) + lane * 8);
#pragma unroll
        for (int k = 0; k < 8; k++) facc[k] = fmaf(w, (float)hv[k], facc[k]);
        den += w;
    }

    const float inv = 1.f / (den + 1e-16f);
    float r[8];
#pragma unroll
    for (int k = 0; k < 8; k++) {
        float v = facc[k] * inv;
        r[k] = (v > 0.f) ? v : expm1f(v);   // elu
    }
    float* ob = &out[(size_t)n * (N_HEADS * OUT_F) + lane * 8];
    *(float4*)(ob)     = make_float4(r[0], r[1], r[2], r[3]);
    *(float4*)(ob + 4) = make_float4(r[4], r[5], r[6], r[7]);
}

extern "C" void kernel_launch(void* const* d_in, const int* in_sizes, int n_in,
                              void* d_out, int out_size, void* d_ws, size_t ws_size,
                              hipStream_t stream) {
    const float* x   = (const float*)d_in[0];
    const int*   src = (const int*)d_in[1];
    const int*   dst = (const int*)d_in[2];
    const float* M   = (const float*)d_in[3];
    const float* W   = (const float*)d_in[4];
    const float* a   = (const float*)d_in[5];
    float* out = (float*)d_out;

    char* p = (char*)d_ws;
    auto alloc = [&](size_t bytes) {
        char* r = p;
        p += (bytes + 255) & ~(size_t)255;
        return r;
    };
    float*  h_ws    = (float*)alloc(sizeof(float) * (size_t)N_NODES * N_HEADS * OUT_F);
    __bf16* hb      = (__bf16*)alloc(sizeof(__bf16) * (size_t)N_NODES * N_HEADS * OUT_F);
    float*  a_self  = (float*)alloc(sizeof(float) * N_NODES * N_HEADS);
    float*  a_neigh = (float*)alloc(sizeof(float) * N_NODES * N_HEADS);
    int*    deg     = (int*)alloc(sizeof(int) * N_NODES);
    int*    start   = (int*)alloc(sizeof(int) * N_NODES);
    int*    cursor  = (int*)alloc(sizeof(int) * N_NODES);
    int*    bsum    = (int*)alloc(sizeof(int) * 256);
    int2*   csr_sm  = (int2*)alloc(sizeof(int2) * N_EDGES);
    __bf16* xb      = (__bf16*)alloc(sizeof(__bf16) * (size_t)N_NODES * IN_F);
    __bf16* Wt      = (__bf16*)alloc(sizeof(__bf16) * N_HEADS * IN_F * OUT_F);

    // --- casts (independent of CSR) ---
    cast_x_kernel<<<N_NODES * IN_F / 4 / 256, 256, 0, stream>>>(x, xb);
    cast_w_kernel<<<(N_HEADS * IN_F * OUT_F + 255) / 256, 256, 0, stream>>>(W, Wt);

    // --- CSR build ---
    hipMemsetAsync(deg, 0, sizeof(int) * N_NODES, stream);
    hist_kernel<<<(N_EDGES + 255) / 256, 256, 0, stream>>>(dst, deg);
    const int nsb = (N_NODES + SB - 1) / SB;
    scanA<<<nsb, SB, 0, stream>>>(deg, start, bsum);
    scanB<<<1, 64, 0, stream>>>(bsum, nsb);
    scanC<<<nsb, SB, 0, stream>>>(start, bsum, cursor);
    fill_kernel<<<(N_EDGES + 255) / 256, 256, 0, stream>>>(src, dst, M, cursor, csr_sm);

    // --- feature transform (bf16 MFMA) ---
    mfma_gemm_kernel<<<(1563 * N_HEADS + 3) / 4, 256, 0, stream>>>(xb, Wt, h_ws);
    cast_h_kernel<<<N_NODES * N_HEADS * OUT_F / 4 / 256, 256, 0, stream>>>(h_ws, hb);
    adot_kernel<<<(N_NODES * N_HEADS) / 4, 256, 0, stream>>>(h_ws, a, a_self, a_neigh);

    // --- fused attention + aggregation + elu (all heads per wave) ---
    agg_kernel<<<(N_NODES + 3) / 4, 256, 0, stream>>>(hb, a_self, a_neigh,
                                                      start, deg, csr_sm, out);
}

// Round 5
// 449.310 us; speedup vs baseline: 2.4482x; 1.1829x over previous
//
#include <hip/hip_runtime.h>
#include <math.h>

#define N_NODES 50000
#define N_EDGES 800000
#define IN_F 256
#define OUT_F 64
#define N_HEADS 8
#define SLOPE 0.2f

typedef __attribute__((ext_vector_type(8))) __bf16 bf16x8;
typedef __attribute__((ext_vector_type(4))) __bf16 bf16x4;
typedef __attribute__((ext_vector_type(4))) float floatx4;

// x fp32 -> bf16, 4 elems/thread (grid exact: 50000*256/4/256 = 12500)
__global__ __launch_bounds__(256) void cast_x_kernel(const float* __restrict__ x,
                                                     __bf16* __restrict__ xb) {
    int i = blockIdx.x * 256 + threadIdx.x;
    float4 v = ((const float4*)x)[i];
    bf16x4 o;
    o[0] = (__bf16)v.x; o[1] = (__bf16)v.y; o[2] = (__bf16)v.z; o[3] = (__bf16)v.w;
    *(bf16x4*)(xb + (size_t)i * 4) = o;
}

// W[h][k][n] fp32 -> Wt[h][n][k] bf16
__global__ __launch_bounds__(256) void cast_w_kernel(const float* __restrict__ W,
                                                     __bf16* __restrict__ Wt) {
    int i = blockIdx.x * 256 + threadIdx.x;
    if (i >= N_HEADS * IN_F * OUT_F) return;
    int n = i & (OUT_F - 1);
    int k = (i >> 6) & (IN_F - 1);
    int h = i >> 14;
    Wt[((size_t)h * OUT_F + n) * IN_F + k] = (__bf16)W[i];
}

// Fused: h = x@W (MFMA, bf16 out via LDS transpose) + a_self/a_neigh dots
// from fp32 accumulators. One wave per (32-node tile, head).
// A[m=lane&15][k=quad*8+j]; B[k][n=lane&15]; D[row=quad*4+reg][col=lane&15].
__global__ __launch_bounds__(256) void mfma_gemm_kernel(const __bf16* __restrict__ xb,
                                                        const __bf16* __restrict__ Wt,
                                                        const float* __restrict__ a,
                                                        __bf16* __restrict__ hb,
                                                        float* __restrict__ a_self,
                                                        float* __restrict__ a_neigh) {
    __shared__ __bf16 lds_t[4][32 * OUT_F];   // 4 waves x 4KB, wave-private
    const int warp = threadIdx.x >> 6;
    const int wid = blockIdx.x * 4 + warp;
    const int head = wid & 7;
    const int tile = wid >> 3;
    if (tile >= 1563) return;
    const int n0 = tile * 32;
    const int lane = threadIdx.x & 63;
    const int l15 = lane & 15;
    const int quad = lane >> 4;

    floatx4 acc[2][4];
#pragma unroll
    for (int i = 0; i < 2; i++)
#pragma unroll
        for (int c = 0; c < 4; c++) acc[i][c] = floatx4{0.f, 0.f, 0.f, 0.f};

    int r0 = n0 + l15;
    int r1 = n0 + 16 + l15;
    r1 = (r1 < N_NODES) ? r1 : (N_NODES - 1);
    const __bf16* xrow0 = xb + (size_t)r0 * IN_F + quad * 8;
    const __bf16* xrow1 = xb + (size_t)r1 * IN_F + quad * 8;
    const __bf16* wbase = Wt + ((size_t)head * OUT_F + l15) * IN_F + quad * 8;

#pragma unroll
    for (int k0 = 0; k0 < IN_F; k0 += 32) {
        bf16x8 a0 = *(const bf16x8*)(xrow0 + k0);
        bf16x8 a1 = *(const bf16x8*)(xrow1 + k0);
#pragma unroll
        for (int c = 0; c < 4; c++) {
            bf16x8 b = *(const bf16x8*)(wbase + (size_t)c * 16 * IN_F + k0);
            acc[0][c] = __builtin_amdgcn_mfma_f32_16x16x32_bf16(a0, b, acc[0][c], 0, 0, 0);
            acc[1][c] = __builtin_amdgcn_mfma_f32_16x16x32_bf16(a1, b, acc[1][c], 0, 0, 0);
        }
    }

    // ---- epilogue 1: attention dots from fp32 acc ----
    float av0[4], av1[4];
#pragma unroll
    for (int c = 0; c < 4; c++) {
        av0[c] = a[head * 2 * OUT_F + c * 16 + l15];            // a[h][0][:]
        av1[c] = a[head * 2 * OUT_F + OUT_F + c * 16 + l15];    // a[h][1][:]
    }
    __bf16* my = lds_t[warp];
#pragma unroll
    for (int i = 0; i < 2; i++) {
#pragma unroll
        for (int reg = 0; reg < 4; reg++) {
            float ps = 0.f, pn = 0.f;
#pragma unroll
            for (int c = 0; c < 4; c++) {
                float v = acc[i][c][reg];
                ps = fmaf(v, av0[c], ps);
                pn = fmaf(v, av1[c], pn);
                my[(i * 16 + quad * 4 + reg) * OUT_F + c * 16 + l15] = (__bf16)v;
            }
#pragma unroll
            for (int off = 1; off < 16; off <<= 1) {
                ps += __shfl_xor(ps, off, 64);
                pn += __shfl_xor(pn, off, 64);
            }
            int node = n0 + i * 16 + quad * 4 + reg;
            if (l15 == 0 && node < N_NODES) {
                a_self[node * N_HEADS + head] = ps;
                a_neigh[node * N_HEADS + head] = pn;
            }
        }
    }
    // ---- epilogue 2: coalesced bf16 h store (wave-private LDS, no barrier) ----
#pragma unroll
    for (int pass = 0; pass < 4; pass++) {
        int row = pass * 8 + (lane >> 3);
        int node = n0 + row;
        bf16x8 v = *(const bf16x8*)&my[row * OUT_F + (lane & 7) * 8];
        if (node < N_NODES)
            *(bf16x8*)(hb + ((size_t)node * N_HEADS + head) * OUT_F + (lane & 7) * 8) = v;
    }
}

__global__ void hist_kernel(const int* __restrict__ dst, int* __restrict__ deg) {
    int e = blockIdx.x * 256 + threadIdx.x;
    if (e < N_EDGES) atomicAdd(&deg[dst[e]], 1);
}

#define SB 512
__global__ void scanA(const int* __restrict__ deg, int* __restrict__ start,
                      int* __restrict__ bsum) {
    __shared__ int tmp[SB];
    int t = threadIdx.x, i = blockIdx.x * SB + t;
    int v = (i < N_NODES) ? deg[i] : 0;
    tmp[t] = v;
    for (int off = 1; off < SB; off <<= 1) {
        __syncthreads();
        int add = (t >= off) ? tmp[t - off] : 0;
        __syncthreads();
        tmp[t] += add;
    }
    if (i < N_NODES) start[i] = tmp[t] - v;
    if (t == SB - 1) bsum[blockIdx.x] = tmp[SB - 1];
}

__global__ void scanB(int* __restrict__ bsum, int nb) {
    if (threadIdx.x == 0 && blockIdx.x == 0) {
        int run = 0;
        for (int b = 0; b < nb; b++) { int v = bsum[b]; bsum[b] = run; run += v; }
    }
}

__global__ void scanC(int* __restrict__ start, const int* __restrict__ bsum,
                      int* __restrict__ cursor) {
    int i = blockIdx.x * SB + threadIdx.x;
    if (i < N_NODES) {
        int s = start[i] + bsum[blockIdx.x];
        start[i] = s;
        cursor[i] = s;
    }
}

// pack {src, m-bits} into one int2 so the agg loop does a single 8B index load
__global__ void fill_kernel(const int* __restrict__ src, const int* __restrict__ dst,
                            const float* __restrict__ M, int* __restrict__ cursor,
                            int2* __restrict__ csr_sm) {
    int e = blockIdx.x * 256 + threadIdx.x;
    if (e < N_EDGES) {
        int d = dst[e];
        int pos = atomicAdd(&cursor[d], 1);
        csr_sm[pos] = make_int2(src[e], __float_as_int(M[e]));
    }
}

// One wave per node, ALL 8 heads per iteration. Lane l: head = l>>3,
// features (l&7)*8..+8. Software-pipelined: index pair, a_self gather and
// the 1KB h-row gather are all issued one edge ahead of the exp/fma chain.
__global__ __launch_bounds__(256) void agg_kernel(const __bf16* __restrict__ hb,
                                                  const float* __restrict__ a_self,
                                                  const float* __restrict__ a_neigh,
                                                  const int* __restrict__ start,
                                                  const int* __restrict__ deg,
                                                  const int2* __restrict__ csr_sm,
                                                  float* __restrict__ out) {
    int n = blockIdx.x * 4 + (threadIdx.x >> 6);
    if (n >= N_NODES) return;
    const int lane = threadIdx.x & 63;
    const int head = lane >> 3;

    const int s0 = start[n];
    const int d = deg[n];
    const float an = a_neigh[n * N_HEADS + head];

    float facc[8];
#pragma unroll
    for (int k = 0; k < 8; k++) facc[k] = 0.f;
    float den = 0.f;

    int2 sm = (d > 0) ? csr_sm[s0] : make_int2(0, 0);
    float as = a_self[sm.x * N_HEADS + head];
    bf16x8 hv = *(const bf16x8*)(hb + (size_t)sm.x * (N_HEADS * OUT_F) + lane * 8);

    for (int j = 0; j < d; j++) {
        // prefetch edge j+1 (index, logit, h-row) before consuming edge j
        int2 sm_n = (j + 1 < d) ? csr_sm[s0 + j + 1] : sm;
        float as_n = a_self[sm_n.x * N_HEADS + head];
        bf16x8 hv_n = *(const bf16x8*)(hb + (size_t)sm_n.x * (N_HEADS * OUT_F) + lane * 8);

        float e = as + an;
        e = (e > 0.f) ? e : SLOPE * e;
        const float w = __expf(e * __int_as_float(sm.y));
#pragma unroll
        for (int k = 0; k < 8; k++) facc[k] = fmaf(w, (float)hv[k], facc[k]);
        den += w;

        sm = sm_n; as = as_n; hv = hv_n;
    }

    const float inv = 1.f / (den + 1e-16f);
    float r[8];
#pragma unroll
    for (int k = 0; k < 8; k++) {
        float v = facc[k] * inv;
        r[k] = (v > 0.f) ? v : expm1f(v);   // elu
    }
    float* ob = &out[(size_t)n * (N_HEADS * OUT_F) + lane * 8];
    *(float4*)(ob)     = make_float4(r[0], r[1], r[2], r[3]);
    *(float4*)(ob + 4) = make_float4(r[4], r[5], r[6], r[7]);
}

extern "C" void kernel_launch(void* const* d_in, const int* in_sizes, int n_in,
                              void* d_out, int out_size, void* d_ws, size_t ws_size,
                              hipStream_t stream) {
    const float* x   = (const float*)d_in[0];
    const int*   src = (const int*)d_in[1];
    const int*   dst = (const int*)d_in[2];
    const float* M   = (const float*)d_in[3];
    const float* W   = (const float*)d_in[4];
    const float* a   = (const float*)d_in[5];
    float* out = (float*)d_out;

    char* p = (char*)d_ws;
    auto alloc = [&](size_t bytes) {
        char* r = p;
        p += (bytes + 255) & ~(size_t)255;
        return r;
    };
    __bf16* hb      = (__bf16*)alloc(sizeof(__bf16) * (size_t)N_NODES * N_HEADS * OUT_F);
    float*  a_self  = (float*)alloc(sizeof(float) * N_NODES * N_HEADS);
    float*  a_neigh = (float*)alloc(sizeof(float) * N_NODES * N_HEADS);
    int*    deg     = (int*)alloc(sizeof(int) * N_NODES);
    int*    start   = (int*)alloc(sizeof(int) * N_NODES);
    int*    cursor  = (int*)alloc(sizeof(int) * N_NODES);
    int*    bsum    = (int*)alloc(sizeof(int) * 256);
    int2*   csr_sm  = (int2*)alloc(sizeof(int2) * N_EDGES);
    __bf16* xb      = (__bf16*)alloc(sizeof(__bf16) * (size_t)N_NODES * IN_F);
    __bf16* Wt      = (__bf16*)alloc(sizeof(__bf16) * N_HEADS * IN_F * OUT_F);

    // --- casts (independent of CSR) ---
    cast_x_kernel<<<N_NODES * IN_F / 4 / 256, 256, 0, stream>>>(x, xb);
    cast_w_kernel<<<(N_HEADS * IN_F * OUT_F + 255) / 256, 256, 0, stream>>>(W, Wt);

    // --- CSR build ---
    hipMemsetAsync(deg, 0, sizeof(int) * N_NODES, stream);
    hist_kernel<<<(N_EDGES + 255) / 256, 256, 0, stream>>>(dst, deg);
    const int nsb = (N_NODES + SB - 1) / SB;
    scanA<<<nsb, SB, 0, stream>>>(deg, start, bsum);
    scanB<<<1, 64, 0, stream>>>(bsum, nsb);
    scanC<<<nsb, SB, 0, stream>>>(start, bsum, cursor);
    fill_kernel<<<(N_EDGES + 255) / 256, 256, 0, stream>>>(src, dst, M, cursor, csr_sm);

    // --- fused feature transform + attention dots (bf16 MFMA) ---
    mfma_gemm_kernel<<<1563 * N_HEADS / 4, 256, 0, stream>>>(xb, Wt, a, hb, a_self, a_neigh);

    // --- fused attention + aggregation + elu (all heads per wave) ---
    agg_kernel<<<(N_NODES + 3) / 4, 256, 0, stream>>>(hb, a_self, a_neigh,
                                                      start, deg, csr_sm, out);
}

// Round 6
// 437.701 us; speedup vs baseline: 2.5131x; 1.0265x over previous
//
#include <hip/hip_runtime.h>
#include <math.h>

#define N_NODES 50000
#define N_EDGES 800000
#define IN_F 256
#define OUT_F 64
#define N_HEADS 8
#define SLOPE 0.2f

typedef __attribute__((ext_vector_type(8))) __bf16 bf16x8;
typedef __attribute__((ext_vector_type(4))) __bf16 bf16x4;
typedef __attribute__((ext_vector_type(4))) float floatx4;

#define CAST_X_BLOCKS 12500   // 50000*256/4/256
#define CAST_W_BLOCKS 512     // 8*256*64/256
#define HIST_BLOCKS   3125    // 800000/256
#define PREP_BLOCKS   (CAST_X_BLOCKS + CAST_W_BLOCKS + HIST_BLOCKS)

// Fused prep: cast x->bf16, cast+transpose W->bf16, dst-degree histogram.
// deg is zeroed by the preceding memset (stream-ordered).
__global__ __launch_bounds__(256) void prep_kernel(const float* __restrict__ x,
                                                   const float* __restrict__ W,
                                                   const int* __restrict__ dst,
                                                   __bf16* __restrict__ xb,
                                                   __bf16* __restrict__ Wt,
                                                   int* __restrict__ deg) {
    const int b = blockIdx.x;
    const int t = threadIdx.x;
    if (b < CAST_X_BLOCKS) {
        int i = b * 256 + t;
        float4 v = ((const float4*)x)[i];
        bf16x4 o;
        o[0] = (__bf16)v.x; o[1] = (__bf16)v.y; o[2] = (__bf16)v.z; o[3] = (__bf16)v.w;
        *(bf16x4*)(xb + (size_t)i * 4) = o;
    } else if (b < CAST_X_BLOCKS + CAST_W_BLOCKS) {
        int i = (b - CAST_X_BLOCKS) * 256 + t;   // exact: 131072 elems
        int n = i & (OUT_F - 1);
        int k = (i >> 6) & (IN_F - 1);
        int h = i >> 14;
        Wt[((size_t)h * OUT_F + n) * IN_F + k] = (__bf16)W[i];
    } else {
        int e = (b - CAST_X_BLOCKS - CAST_W_BLOCKS) * 256 + t;  // exact: 800000
        atomicAdd(&deg[dst[e]], 1);
    }
}

// Fused GEMM: one block per 32-node tile, x staged in LDS once, each of the
// 4 waves computes 2 heads (128 MFMA). Epilogue: a_self/a_neigh dots from
// fp32 acc + bf16 h store via wave-private LDS transpose (LDS reused).
// A[m=lane&15][k=quad*8+j]; B[k][n=lane&15]; D[row=quad*4+reg][col=lane&15].
#define XPAD 264   // 256 + 8 bf16 pad: 528B row stride -> 2-way banks (free)
__global__ __launch_bounds__(256) void mfma_gemm_kernel(const __bf16* __restrict__ xb,
                                                        const __bf16* __restrict__ Wt,
                                                        const float* __restrict__ a,
                                                        __bf16* __restrict__ hb,
                                                        float* __restrict__ a_self,
                                                        float* __restrict__ a_neigh) {
    __shared__ __bf16 xs[32][XPAD];
    const int warp = threadIdx.x >> 6;
    const int tile = blockIdx.x;              // 0..1562
    const int n0 = tile * 32;
    const int lane = threadIdx.x & 63;
    const int l15 = lane & 15;
    const int quad = lane >> 4;
    const int h0 = warp * 2;

    // ---- stage x tile (32 rows x 256 k), clamp tail rows ----
#pragma unroll
    for (int i = 0; i < 4; i++) {
        int idx = i * 256 + threadIdx.x;      // 0..1023, 8 bf16 each
        int row = idx >> 5;
        int col = (idx & 31) * 8;
        int node = n0 + row;
        node = (node < N_NODES) ? node : (N_NODES - 1);
        *(bf16x8*)&xs[row][col] = *(const bf16x8*)(xb + (size_t)node * IN_F + col);
    }
    __syncthreads();

    floatx4 acc[2][2][4];   // [head][rowblock][col]
#pragma unroll
    for (int hh = 0; hh < 2; hh++)
#pragma unroll
        for (int i = 0; i < 2; i++)
#pragma unroll
            for (int c = 0; c < 4; c++) acc[hh][i][c] = floatx4{0.f, 0.f, 0.f, 0.f};

    const __bf16* wb0 = Wt + ((size_t)h0 * OUT_F + l15) * IN_F + quad * 8;
    const __bf16* wb1 = wb0 + (size_t)OUT_F * IN_F;

#pragma unroll
    for (int k0 = 0; k0 < IN_F; k0 += 32) {
        bf16x8 a0 = *(const bf16x8*)&xs[l15][k0 + quad * 8];
        bf16x8 a1 = *(const bf16x8*)&xs[l15 + 16][k0 + quad * 8];
#pragma unroll
        for (int c = 0; c < 4; c++) {
            bf16x8 b0 = *(const bf16x8*)(wb0 + (size_t)c * 16 * IN_F + k0);
            acc[0][0][c] = __builtin_amdgcn_mfma_f32_16x16x32_bf16(a0, b0, acc[0][0][c], 0, 0, 0);
            acc[0][1][c] = __builtin_amdgcn_mfma_f32_16x16x32_bf16(a1, b0, acc[0][1][c], 0, 0, 0);
            bf16x8 b1 = *(const bf16x8*)(wb1 + (size_t)c * 16 * IN_F + k0);
            acc[1][0][c] = __builtin_amdgcn_mfma_f32_16x16x32_bf16(a0, b1, acc[1][0][c], 0, 0, 0);
            acc[1][1][c] = __builtin_amdgcn_mfma_f32_16x16x32_bf16(a1, b1, acc[1][1][c], 0, 0, 0);
        }
    }

    __syncthreads();   // all waves done reading xs; reuse as transpose buffer
    __bf16* my = (__bf16*)xs + warp * (32 * OUT_F);

#pragma unroll
    for (int hh = 0; hh < 2; hh++) {
        const int head = h0 + hh;
        float av0[4], av1[4];
#pragma unroll
        for (int c = 0; c < 4; c++) {
            av0[c] = a[head * 2 * OUT_F + c * 16 + l15];
            av1[c] = a[head * 2 * OUT_F + OUT_F + c * 16 + l15];
        }
#pragma unroll
        for (int i = 0; i < 2; i++) {
#pragma unroll
            for (int reg = 0; reg < 4; reg++) {
                float ps = 0.f, pn = 0.f;
#pragma unroll
                for (int c = 0; c < 4; c++) {
                    float v = acc[hh][i][c][reg];
                    ps = fmaf(v, av0[c], ps);
                    pn = fmaf(v, av1[c], pn);
                    my[(i * 16 + quad * 4 + reg) * OUT_F + c * 16 + l15] = (__bf16)v;
                }
#pragma unroll
                for (int off = 1; off < 16; off <<= 1) {
                    ps += __shfl_xor(ps, off, 64);
                    pn += __shfl_xor(pn, off, 64);
                }
                int node = n0 + i * 16 + quad * 4 + reg;
                if (l15 == 0 && node < N_NODES) {
                    a_self[node * N_HEADS + head] = ps;
                    a_neigh[node * N_HEADS + head] = pn;
                }
            }
        }
        // coalesced bf16 h store (wave-private region, in-wave ordering)
#pragma unroll
        for (int pass = 0; pass < 4; pass++) {
            int row = pass * 8 + (lane >> 3);
            int node = n0 + row;
            bf16x8 v = *(const bf16x8*)&my[row * OUT_F + (lane & 7) * 8];
            if (node < N_NODES)
                *(bf16x8*)(hb + ((size_t)node * N_HEADS + head) * OUT_F + (lane & 7) * 8) = v;
        }
    }
}

#define SB 512
#define NSB 98   // ceil(50000/512)
__global__ void scanA(const int* __restrict__ deg, int* __restrict__ start,
                      int* __restrict__ bsum) {
    __shared__ int tmp[SB];
    int t = threadIdx.x, i = blockIdx.x * SB + t;
    int v = (i < N_NODES) ? deg[i] : 0;
    tmp[t] = v;
    for (int off = 1; off < SB; off <<= 1) {
        __syncthreads();
        int add = (t >= off) ? tmp[t - off] : 0;
        __syncthreads();
        tmp[t] += add;
    }
    if (i < N_NODES) start[i] = tmp[t] - v;
    if (t == SB - 1) bsum[blockIdx.x] = tmp[SB - 1];
}

// scanC with inlined second-level scan of the 98 block sums (Hillis-Steele
// over 128 lanes) — replaces the serial single-thread scanB dispatch.
__global__ void scanC(int* __restrict__ start, const int* __restrict__ bsum,
                      int* __restrict__ cursor) {
    __shared__ int pre[128];
    int t = threadIdx.x;
    if (t < 128) pre[t] = (t < NSB) ? bsum[t] : 0;
    __syncthreads();
    for (int off = 1; off < 128; off <<= 1) {
        int add = (t < 128 && t >= off) ? pre[t - off] : 0;
        __syncthreads();
        if (t < 128) pre[t] += add;
        __syncthreads();
    }
    int excl = (blockIdx.x == 0) ? 0 : pre[blockIdx.x - 1];
    int i = blockIdx.x * SB + t;
    if (i < N_NODES) {
        int s = start[i] + excl;
        start[i] = s;
        cursor[i] = s;
    }
}

// pack {src, m-bits} into one int2 so the agg loop does a single 8B index load
__global__ void fill_kernel(const int* __restrict__ src, const int* __restrict__ dst,
                            const float* __restrict__ M, int* __restrict__ cursor,
                            int2* __restrict__ csr_sm) {
    int e = blockIdx.x * 256 + threadIdx.x;
    if (e < N_EDGES) {
        int d = dst[e];
        int pos = atomicAdd(&cursor[d], 1);
        csr_sm[pos] = make_int2(src[e], __float_as_int(M[e]));
    }
}

// One wave per node, ALL 8 heads per iteration. Lane l: head = l>>3,
// features (l&7)*8..+8. Software-pipelined gather (index, logit, h-row
// issued one edge ahead). Memory-bound at ~4 TB/s fabric gather.
__global__ __launch_bounds__(256) void agg_kernel(const __bf16* __restrict__ hb,
                                                  const float* __restrict__ a_self,
                                                  const float* __restrict__ a_neigh,
                                                  const int* __restrict__ start,
                                                  const int* __restrict__ deg,
                                                  const int2* __restrict__ csr_sm,
                                                  float* __restrict__ out) {
    int n = blockIdx.x * 4 + (threadIdx.x >> 6);
    if (n >= N_NODES) return;
    const int lane = threadIdx.x & 63;
    const int head = lane >> 3;

    const int s0 = start[n];
    const int d = deg[n];
    const float an = a_neigh[n * N_HEADS + head];

    float facc[8];
#pragma unroll
    for (int k = 0; k < 8; k++) facc[k] = 0.f;
    float den = 0.f;

    int2 sm = (d > 0) ? csr_sm[s0] : make_int2(0, 0);
    float as = a_self[sm.x * N_HEADS + head];
    bf16x8 hv = *(const bf16x8*)(hb + (size_t)sm.x * (N_HEADS * OUT_F) + lane * 8);

    for (int j = 0; j < d; j++) {
        int2 sm_n = (j + 1 < d) ? csr_sm[s0 + j + 1] : sm;
        float as_n = a_self[sm_n.x * N_HEADS + head];
        bf16x8 hv_n = *(const bf16x8*)(hb + (size_t)sm_n.x * (N_HEADS * OUT_F) + lane * 8);

        float e = as + an;
        e = (e > 0.f) ? e : SLOPE * e;
        const float w = __expf(e * __int_as_float(sm.y));
#pragma unroll
        for (int k = 0; k < 8; k++) facc[k] = fmaf(w, (float)hv[k], facc[k]);
        den += w;

        sm = sm_n; as = as_n; hv = hv_n;
    }

    const float inv = 1.f / (den + 1e-16f);
    float r[8];
#pragma unroll
    for (int k = 0; k < 8; k++) {
        float v = facc[k] * inv;
        r[k] = (v > 0.f) ? v : expm1f(v);   // elu
    }
    float* ob = &out[(size_t)n * (N_HEADS * OUT_F) + lane * 8];
    *(float4*)(ob)     = make_float4(r[0], r[1], r[2], r[3]);
    *(float4*)(ob + 4) = make_float4(r[4], r[5], r[6], r[7]);
}

extern "C" void kernel_launch(void* const* d_in, const int* in_sizes, int n_in,
                              void* d_out, int out_size, void* d_ws, size_t ws_size,
                              hipStream_t stream) {
    const float* x   = (const float*)d_in[0];
    const int*   src = (const int*)d_in[1];
    const int*   dst = (const int*)d_in[2];
    const float* M   = (const float*)d_in[3];
    const float* W   = (const float*)d_in[4];
    const float* a   = (const float*)d_in[5];
    float* out = (float*)d_out;

    char* p = (char*)d_ws;
    auto alloc = [&](size_t bytes) {
        char* r = p;
        p += (bytes + 255) & ~(size_t)255;
        return r;
    };
    __bf16* hb      = (__bf16*)alloc(sizeof(__bf16) * (size_t)N_NODES * N_HEADS * OUT_F);
    float*  a_self  = (float*)alloc(sizeof(float) * N_NODES * N_HEADS);
    float*  a_neigh = (float*)alloc(sizeof(float) * N_NODES * N_HEADS);
    int*    deg     = (int*)alloc(sizeof(int) * N_NODES);
    int*    start   = (int*)alloc(sizeof(int) * N_NODES);
    int*    cursor  = (int*)alloc(sizeof(int) * N_NODES);
    int*    bsum    = (int*)alloc(sizeof(int) * 256);
    int2*   csr_sm  = (int2*)alloc(sizeof(int2) * N_EDGES);
    __bf16* xb      = (__bf16*)alloc(sizeof(__bf16) * (size_t)N_NODES * IN_F);
    __bf16* Wt      = (__bf16*)alloc(sizeof(__bf16) * N_HEADS * IN_F * OUT_F);

    // --- prep: zero deg, then fused cast_x + cast_w + hist ---
    hipMemsetAsync(deg, 0, sizeof(int) * N_NODES, stream);
    prep_kernel<<<PREP_BLOCKS, 256, 0, stream>>>(x, W, dst, xb, Wt, deg);

    // --- CSR scan + fill ---
    scanA<<<NSB, SB, 0, stream>>>(deg, start, bsum);
    scanC<<<NSB, SB, 0, stream>>>(start, bsum, cursor);
    fill_kernel<<<(N_EDGES + 255) / 256, 256, 0, stream>>>(src, dst, M, cursor, csr_sm);

    // --- fused feature transform + attention dots (bf16 MFMA, x in LDS) ---
    mfma_gemm_kernel<<<1563, 256, 0, stream>>>(xb, Wt, a, hb, a_self, a_neigh);

    // --- fused attention + aggregation + elu (all heads per wave) ---
    agg_kernel<<<(N_NODES + 3) / 4, 256, 0, stream>>>(hb, a_self, a_neigh,
                                                      start, deg, csr_sm, out);
}